// Round 2
// baseline (52.924 us; speedup 1.0000x reference)
//
#include <hip/hip_runtime.h>

#define B_ 4
#define T_ 4096
#define D_ 2048
#define W_ 4
#define D4_ (D_ / 4)          // 512 float4 per row
#define TCHUNK 16
#define NTC (T_ / TCHUNK)     // 256 chunks

__device__ __forceinline__ float silu_f(float v) {
    return v / (1.0f + __expf(-v));
}

__global__ __launch_bounds__(256) void conv_silu_kernel(
    const float* __restrict__ x, const float* __restrict__ w,
    float* __restrict__ out)
{
    int gid = blockIdx.x * blockDim.x + threadIdx.x;   // 0 .. B*NTC*D4-1
    int d4   = gid & (D4_ - 1);          // consecutive threads -> consecutive d4 (coalesced)
    int rest = gid / D4_;
    int tc   = rest & (NTC - 1);
    int b    = rest / NTC;

    const float4* x4 = (const float4*)x;
    const float4* w4 = (const float4*)w;
    float4*       y4 = (float4*)out;

    // depthwise taps for these 4 channels (tap W-1 hits the current token)
    float4 w0 = w4[0 * D4_ + d4];
    float4 w1 = w4[1 * D4_ + d4];
    float4 w2 = w4[2 * D4_ + d4];
    float4 w3 = w4[3 * D4_ + d4];

    int   t0   = tc * TCHUNK;
    long  base = (long)b * T_ * D4_;     // in float4 units

    float4 zero = make_float4(0.f, 0.f, 0.f, 0.f);
    // sliding window of the 3 previous tokens (zero-padded at t<0)
    float4 xm3 = (t0 >= 3) ? x4[base + (long)(t0 - 3) * D4_ + d4] : zero;
    float4 xm2 = (t0 >= 2) ? x4[base + (long)(t0 - 2) * D4_ + d4] : zero;
    float4 xm1 = (t0 >= 1) ? x4[base + (long)(t0 - 1) * D4_ + d4] : zero;

    #pragma unroll 4
    for (int t = t0; t < t0 + TCHUNK; ++t) {
        float4 x0 = x4[base + (long)t * D4_ + d4];
        float4 y;
        y.x = w0.x * xm3.x + w1.x * xm2.x + w2.x * xm1.x + w3.x * x0.x;
        y.y = w0.y * xm3.y + w1.y * xm2.y + w2.y * xm1.y + w3.y * x0.y;
        y.z = w0.z * xm3.z + w1.z * xm2.z + w2.z * xm1.z + w3.z * x0.z;
        y.w = w0.w * xm3.w + w1.w * xm2.w + w2.w * xm1.w + w3.w * x0.w;
        y.x = silu_f(y.x);
        y.y = silu_f(y.y);
        y.z = silu_f(y.z);
        y.w = silu_f(y.w);
        y4[base + (long)t * D4_ + d4] = y;
        xm3 = xm2; xm2 = xm1; xm1 = x0;
    }

    // Fused final_state: the last t-chunk's threads also emit x[:, T-4:, :].
    // These 4 loads are L2-hot (just read them in the loop above).
    if (tc == NTC - 1) {
        float4* o4 = (float4*)out + ((long)B_ * T_ * D_) / 4;
        #pragma unroll
        for (int k = 0; k < W_; ++k) {
            o4[((long)b * W_ + k) * D4_ + d4] =
                x4[base + (long)(T_ - W_ + k) * D4_ + d4];
        }
    }
}

extern "C" void kernel_launch(void* const* d_in, const int* in_sizes, int n_in,
                              void* d_out, int out_size, void* d_ws, size_t ws_size,
                              hipStream_t stream) {
    const float* x = (const float*)d_in[0];
    const float* w = (const float*)d_in[1];
    float* out = (float*)d_out;

    int total_main = B_ * NTC * D4_;          // 524288 threads
    conv_silu_kernel<<<total_main / 256, 256, 0, stream>>>(x, w, out);
}

// Round 3
// 49.074 us; speedup vs baseline: 1.0784x; 1.0784x over previous
//
#include <hip/hip_runtime.h>

#define B_ 4
#define T_ 4096
#define D_ 2048
#define W_ 4
#define D4_ (D_ / 4)          // 512 float4 per row
#define TCHUNK 16
#define NTC (T_ / TCHUNK)     // 256 chunks

typedef float f4 __attribute__((ext_vector_type(4)));

__device__ __forceinline__ f4 silu4(f4 v) {
    f4 r;
    r.x = v.x / (1.0f + __expf(-v.x));
    r.y = v.y / (1.0f + __expf(-v.y));
    r.z = v.z / (1.0f + __expf(-v.z));
    r.w = v.w / (1.0f + __expf(-v.w));
    return r;
}

__global__ __launch_bounds__(256) void conv_silu_kernel(
    const float* __restrict__ x, const float* __restrict__ w,
    float* __restrict__ out)
{
    int gid = blockIdx.x * blockDim.x + threadIdx.x;   // 0 .. B*NTC*D4-1
    int d4   = gid & (D4_ - 1);          // consecutive threads -> consecutive d4 (coalesced)
    int rest = gid >> 9;                 // / D4_
    int tc   = rest & (NTC - 1);
    int b    = rest >> 8;                // / NTC

    const f4* x4 = (const f4*)x;
    const f4* w4 = (const f4*)w;
    f4*       y4 = (f4*)out;

    // depthwise taps for these 4 channels (tap W-1 hits the current token)
    f4 w0 = w4[0 * D4_ + d4];
    f4 w1 = w4[1 * D4_ + d4];
    f4 w2 = w4[2 * D4_ + d4];
    f4 w3 = w4[3 * D4_ + d4];

    int t0   = tc * TCHUNK;
    int base = b * (T_ * D4_) + d4;      // in f4 units; max < 2^23, fits int

    f4 zero = (f4)0.0f;
    // sliding window of the 3 previous tokens (zero-padded at t<0)
    f4 xm3 = (t0 >= 3) ? x4[base + (t0 - 3) * D4_] : zero;
    f4 xm2 = (t0 >= 2) ? x4[base + (t0 - 2) * D4_] : zero;
    f4 xm1 = (t0 >= 1) ? x4[base + (t0 - 1) * D4_] : zero;

    #pragma unroll 4
    for (int t = t0; t < t0 + TCHUNK; ++t) {
        f4 x0 = x4[base + t * D4_];
        f4 y = w0 * xm3 + w1 * xm2 + w2 * xm1 + w3 * x0;
        y = silu4(y);
        // y is write-once, never re-read: nontemporal store keeps x L3-resident
        __builtin_nontemporal_store(y, &y4[base + t * D4_]);
        xm3 = xm2; xm2 = xm1; xm1 = x0;
    }

    // Fused final_state: the last t-chunk's threads also emit x[:, T-4:, :].
    if (tc == NTC - 1) {
        f4* o4 = (f4*)out + (B_ * T_ * D_) / 4;
        #pragma unroll
        for (int k = 0; k < W_; ++k) {
            f4 v = x4[base + (T_ - W_ + k) * D4_];
            __builtin_nontemporal_store(v, &o4[(b * W_ + k) * D4_ + d4]);
        }
    }
}

extern "C" void kernel_launch(void* const* d_in, const int* in_sizes, int n_in,
                              void* d_out, int out_size, void* d_ws, size_t ws_size,
                              hipStream_t stream) {
    const float* x = (const float*)d_in[0];
    const float* w = (const float*)d_in[1];
    float* out = (float*)d_out;

    int total_main = B_ * NTC * D4_;          // 524288 threads
    conv_silu_kernel<<<total_main / 256, 256, 0, stream>>>(x, w, out);
}

// Round 4
// 47.206 us; speedup vs baseline: 1.1211x; 1.0396x over previous
//
#include <hip/hip_runtime.h>

#define B_ 4
#define T_ 4096
#define D_ 2048
#define W_ 4
#define D4_ (D_ / 4)          // 512 float4 per row
#define TCHUNK 32
#define NTC (T_ / TCHUNK)     // 128 chunks

typedef float f4 __attribute__((ext_vector_type(4)));

__device__ __forceinline__ float silu_f(float v) {
    // v * rcp(1+exp(-v)) : v_exp_f32 + v_rcp_f32, ~1ulp rcp — threshold is 8.8e-2
    return v * __builtin_amdgcn_rcpf(1.0f + __expf(-v));
}

__device__ __forceinline__ f4 silu4(f4 v) {
    f4 r;
    r.x = silu_f(v.x);
    r.y = silu_f(v.y);
    r.z = silu_f(v.z);
    r.w = silu_f(v.w);
    return r;
}

__global__ __launch_bounds__(256) void conv_silu_kernel(
    const float* __restrict__ x, const float* __restrict__ w,
    float* __restrict__ out)
{
    int gid = blockIdx.x * blockDim.x + threadIdx.x;   // 0 .. B*NTC*D4-1
    int d4   = gid & (D4_ - 1);          // consecutive threads -> consecutive d4 (coalesced)
    int rest = gid >> 9;                 // / D4_
    int tc   = rest & (NTC - 1);
    int b    = rest >> 7;                // / NTC

    const f4* x4 = (const f4*)x;
    const f4* w4 = (const f4*)w;
    f4*       y4 = (f4*)out;

    // depthwise taps for these 4 channels (tap W-1 hits the current token)
    f4 w0 = w4[0 * D4_ + d4];
    f4 w1 = w4[1 * D4_ + d4];
    f4 w2 = w4[2 * D4_ + d4];
    f4 w3 = w4[3 * D4_ + d4];

    int t0   = tc * TCHUNK;
    int base = b * (T_ * D4_) + d4;      // in f4 units; fits int

    f4 zero = (f4)0.0f;
    // sliding window of the 3 previous tokens (zero-padded at t<0)
    f4 xm3 = (t0 >= 3) ? x4[base + (t0 - 3) * D4_] : zero;
    f4 xm2 = (t0 >= 2) ? x4[base + (t0 - 2) * D4_] : zero;
    f4 xm1 = (t0 >= 1) ? x4[base + (t0 - 1) * D4_] : zero;

    #pragma unroll 4
    for (int t = t0; t < t0 + TCHUNK; ++t) {
        f4 x0 = x4[base + t * D4_];
        f4 y = w0 * xm3 + w1 * xm2 + w2 * xm1 + w3 * x0;
        y = silu4(y);
        // y is write-once, never re-read
        __builtin_nontemporal_store(y, &y4[base + t * D4_]);
        xm3 = xm2; xm2 = xm1; xm1 = x0;
    }

    // Fused final_state: the last t-chunk's threads also emit x[:, T-4:, :].
    if (tc == NTC - 1) {
        f4* o4 = (f4*)out + (B_ * T_ * D_) / 4;
        #pragma unroll
        for (int k = 0; k < W_; ++k) {
            f4 v = x4[base + (T_ - W_ + k) * D4_];
            __builtin_nontemporal_store(v, &o4[(b * W_ + k) * D4_ + d4]);
        }
    }
}

extern "C" void kernel_launch(void* const* d_in, const int* in_sizes, int n_in,
                              void* d_out, int out_size, void* d_ws, size_t ws_size,
                              hipStream_t stream) {
    const float* x = (const float*)d_in[0];
    const float* w = (const float*)d_in[1];
    float* out = (float*)d_out;

    int total_main = B_ * NTC * D4_;          // 262144 threads
    conv_silu_kernel<<<total_main / 256, 256, 0, stream>>>(x, w, out);
}

// Round 5
// 46.645 us; speedup vs baseline: 1.1346x; 1.0120x over previous
//
#include <hip/hip_runtime.h>

#define B_ 4
#define T_ 4096
#define D_ 2048
#define W_ 4
#define D4_ (D_ / 4)          // 512 float4 per row
#define TCHUNK 32
#define NTC (T_ / TCHUNK)     // 128 chunks
#define IB 8                  // inner block: loads issued back-to-back

typedef float f4 __attribute__((ext_vector_type(4)));

__device__ __forceinline__ float silu_f(float v) {
    return v * __builtin_amdgcn_rcpf(1.0f + __expf(-v));
}

__device__ __forceinline__ f4 silu4(f4 v) {
    f4 r;
    r.x = silu_f(v.x);
    r.y = silu_f(v.y);
    r.z = silu_f(v.z);
    r.w = silu_f(v.w);
    return r;
}

__global__ __launch_bounds__(256) void conv_silu_kernel(
    const float* __restrict__ x, const float* __restrict__ w,
    float* __restrict__ out)
{
    int gid = blockIdx.x * blockDim.x + threadIdx.x;   // 0 .. B*NTC*D4-1
    int d4   = gid & (D4_ - 1);          // consecutive threads -> consecutive d4 (coalesced)
    int rest = gid >> 9;                 // / D4_
    int tc   = rest & (NTC - 1);
    int b    = rest >> 7;                // / NTC

    const f4* x4 = (const f4*)x;
    const f4* w4 = (const f4*)w;
    f4*       y4 = (f4*)out;

    // depthwise taps for these 4 channels (tap W-1 hits the current token)
    f4 w0 = w4[0 * D4_ + d4];
    f4 w1 = w4[1 * D4_ + d4];
    f4 w2 = w4[2 * D4_ + d4];
    f4 w3 = w4[3 * D4_ + d4];

    int t0   = tc * TCHUNK;
    int base = b * (T_ * D4_) + d4;      // in f4 units; fits int

    f4 zero = (f4)0.0f;
    // sliding window of the 3 previous tokens (zero-padded at t<0)
    f4 xm3 = (t0 >= 3) ? x4[base + (t0 - 3) * D4_] : zero;
    f4 xm2 = (t0 >= 2) ? x4[base + (t0 - 2) * D4_] : zero;
    f4 xm1 = (t0 >= 1) ? x4[base + (t0 - 1) * D4_] : zero;

    #pragma unroll
    for (int tb = 0; tb < TCHUNK; tb += IB) {
        // 1) issue IB loads back-to-back (static indices -> registers)
        f4 xv[IB];
        #pragma unroll
        for (int i = 0; i < IB; ++i)
            xv[i] = x4[base + (t0 + tb + i) * D4_];

        // 2) compute
        f4 yv[IB];
        yv[0] = w0 * xm3   + w1 * xm2   + w2 * xm1   + w3 * xv[0];
        yv[1] = w0 * xm2   + w1 * xm1   + w2 * xv[0] + w3 * xv[1];
        yv[2] = w0 * xm1   + w1 * xv[0] + w2 * xv[1] + w3 * xv[2];
        #pragma unroll
        for (int i = 3; i < IB; ++i)
            yv[i] = w0 * xv[i-3] + w1 * xv[i-2] + w2 * xv[i-1] + w3 * xv[i];

        // 3) store IB outputs (write-once, nontemporal)
        #pragma unroll
        for (int i = 0; i < IB; ++i)
            __builtin_nontemporal_store(silu4(yv[i]), &y4[base + (t0 + tb + i) * D4_]);

        xm3 = xv[IB-3]; xm2 = xv[IB-2]; xm1 = xv[IB-1];
    }

    // Fused final_state: the last t-chunk's threads also emit x[:, T-4:, :].
    // Window regs hold x[T-3..T-1]; only x[T-4] needs a (L2-hot) reload.
    if (tc == NTC - 1) {
        f4* o4 = (f4*)out + (B_ * T_ * D_) / 4;
        f4 v0 = x4[base + (T_ - 4) * D4_];
        __builtin_nontemporal_store(v0,  &o4[(b * W_ + 0) * D4_ + d4]);
        __builtin_nontemporal_store(xm3, &o4[(b * W_ + 1) * D4_ + d4]);
        __builtin_nontemporal_store(xm2, &o4[(b * W_ + 2) * D4_ + d4]);
        __builtin_nontemporal_store(xm1, &o4[(b * W_ + 3) * D4_ + d4]);
    }
}

extern "C" void kernel_launch(void* const* d_in, const int* in_sizes, int n_in,
                              void* d_out, int out_size, void* d_ws, size_t ws_size,
                              hipStream_t stream) {
    const float* x = (const float*)d_in[0];
    const float* w = (const float*)d_in[1];
    float* out = (float*)d_out;

    int total_main = B_ * NTC * D4_;          // 262144 threads
    conv_silu_kernel<<<total_main / 256, 256, 0, stream>>>(x, w, out);
}

// Round 6
// 46.604 us; speedup vs baseline: 1.1356x; 1.0009x over previous
//
#include <hip/hip_runtime.h>

#define B_ 4
#define T_ 4096
#define D_ 2048
#define W_ 4
#define D4_ (D_ / 4)          // 512 float4 per row
#define TCHUNK 32
#define NTC (T_ / TCHUNK)     // 128 chunks
#define IB 16                 // inner block: loads issued back-to-back

typedef float f4 __attribute__((ext_vector_type(4)));

__device__ __forceinline__ float silu_f(float v) {
    return v * __builtin_amdgcn_rcpf(1.0f + __expf(-v));
}

__device__ __forceinline__ f4 silu4(f4 v) {
    f4 r;
    r.x = silu_f(v.x);
    r.y = silu_f(v.y);
    r.z = silu_f(v.z);
    r.w = silu_f(v.w);
    return r;
}

__global__ __launch_bounds__(256, 4) void conv_silu_kernel(
    const float* __restrict__ x, const float* __restrict__ w,
    float* __restrict__ out)
{
    int gid = blockIdx.x * blockDim.x + threadIdx.x;   // 0 .. B*NTC*D4-1
    int d4   = gid & (D4_ - 1);          // consecutive threads -> consecutive d4 (coalesced)
    int rest = gid >> 9;                 // / D4_
    int tc   = rest & (NTC - 1);
    int b    = rest >> 7;                // / NTC

    const f4* x4 = (const f4*)x;
    const f4* w4 = (const f4*)w;
    f4*       y4 = (f4*)out;

    // depthwise taps for these 4 channels (tap W-1 hits the current token)
    f4 w0 = w4[0 * D4_ + d4];
    f4 w1 = w4[1 * D4_ + d4];
    f4 w2 = w4[2 * D4_ + d4];
    f4 w3 = w4[3 * D4_ + d4];

    int t0   = tc * TCHUNK;
    int base = b * (T_ * D4_) + d4;      // in f4 units; fits int

    f4 zero = (f4)0.0f;
    // sliding window of the 3 previous tokens (zero-padded at t<0)
    f4 xm3 = (t0 >= 3) ? x4[base + (t0 - 3) * D4_] : zero;
    f4 xm2 = (t0 >= 2) ? x4[base + (t0 - 2) * D4_] : zero;
    f4 xm1 = (t0 >= 1) ? x4[base + (t0 - 1) * D4_] : zero;

    #pragma unroll
    for (int tb = 0; tb < TCHUNK; tb += IB) {
        // 1) issue IB loads back-to-back (static indices -> registers)
        f4 xv[IB];
        #pragma unroll
        for (int i = 0; i < IB; ++i)
            xv[i] = x4[base + (t0 + tb + i) * D4_];

        // 2) compute
        f4 yv[IB];
        yv[0] = w0 * xm3   + w1 * xm2   + w2 * xm1   + w3 * xv[0];
        yv[1] = w0 * xm2   + w1 * xm1   + w2 * xv[0] + w3 * xv[1];
        yv[2] = w0 * xm1   + w1 * xv[0] + w2 * xv[1] + w3 * xv[2];
        #pragma unroll
        for (int i = 3; i < IB; ++i)
            yv[i] = w0 * xv[i-3] + w1 * xv[i-2] + w2 * xv[i-1] + w3 * xv[i];

        // 3) store IB outputs (write-once, nontemporal)
        #pragma unroll
        for (int i = 0; i < IB; ++i)
            __builtin_nontemporal_store(silu4(yv[i]), &y4[base + (t0 + tb + i) * D4_]);

        xm3 = xv[IB-3]; xm2 = xv[IB-2]; xm1 = xv[IB-1];
    }

    // Fused final_state: the last t-chunk's threads also emit x[:, T-4:, :].
    // Window regs hold x[T-3..T-1]; only x[T-4] needs a (L2-hot) reload.
    if (tc == NTC - 1) {
        f4* o4 = (f4*)out + (B_ * T_ * D_) / 4;
        f4 v0 = x4[base + (T_ - 4) * D4_];
        __builtin_nontemporal_store(v0,  &o4[(b * W_ + 0) * D4_ + d4]);
        __builtin_nontemporal_store(xm3, &o4[(b * W_ + 1) * D4_ + d4]);
        __builtin_nontemporal_store(xm2, &o4[(b * W_ + 2) * D4_ + d4]);
        __builtin_nontemporal_store(xm1, &o4[(b * W_ + 3) * D4_ + d4]);
    }
}

extern "C" void kernel_launch(void* const* d_in, const int* in_sizes, int n_in,
                              void* d_out, int out_size, void* d_ws, size_t ws_size,
                              hipStream_t stream) {
    const float* x = (const float*)d_in[0];
    const float* w = (const float*)d_in[1];
    float* out = (float*)d_out;

    int total_main = B_ * NTC * D4_;          // 262144 threads
    conv_silu_kernel<<<total_main / 256, 256, 0, stream>>>(x, w, out);
}